// Round 6
// baseline (193.033 us; speedup 1.0000x reference)
//
#include <hip/hip_runtime.h>

// ComboSumModule: six independent sum-over-axis-1 reductions (f32).
// Shapes: (2048,128,64) (2048,32,32) (2048,64,64) (2048,16,48)
//         (2048,200,32) (2048,8,8). Outputs concatenated flat.
//
// R1-R5 post-mortem: five structurally different column-slab kernels all
// pinned at 58-64us / 1.45 TB/s with VALUBusy ~1.5% -- the memory system
// serves the strided column-walk at ~1/10 streaming rate, and the compiler
// caps per-wave MLP at 2-3 loads regardless of source structure. The one
// never-changed variable: stride. R6: each wave streams a CONTIGUOUS chunk
// (one batch's MxN block, sequential 1KB wave-loads), accumulates
// (row-class, col) partials in-register, folds row-classes with a
// __shfl_xor butterfly, lanes 0..N4-1 store. No LDS, no barriers.
// x3 (N=48, N4=12 doesn't divide 64) keeps the old column scheme (3.7%).

__device__ __forceinline__ float4 f4add(float4 a, float4 b) {
  return make_float4(a.x + b.x, a.y + b.y, a.z + b.z, a.w + b.w);
}

__device__ __forceinline__ float4 f4shfl_xor(float4 v, int mask) {
  return make_float4(__shfl_xor(v.x, mask), __shfl_xor(v.y, mask),
                     __shfl_xor(v.z, mask), __shfl_xor(v.w, mask));
}

// One wave reduces CHUNKS whole batches of an (B, M, N4*4) tensor.
// Chunk = M*N4 float4s, contiguous; LOADS = M*N4/64 sequential wave-loads.
// Lane L accumulates rows {i*RPL + L/N4} of col (L%N4); butterfly over
// masks N4..32 folds the RPL... row classes; lanes 0..N4-1 store.
template <int M, int N4, int CHUNKS>
__device__ __forceinline__ void stream_sum(const float* __restrict__ xp,
                                           float* __restrict__ out,
                                           int out_base4, int first_batch,
                                           int lane) {
  constexpr int LOADS = (M * N4) / 64;
  static_assert((M * N4) % 64 == 0 && 64 % N4 == 0, "layout");
  const int col = lane & (N4 - 1);
#pragma unroll
  for (int c = 0; c < CHUNKS; ++c) {
    const int b = first_batch + c;
    const float4* __restrict__ p =
        reinterpret_cast<const float4*>(xp) + (size_t)b * (M * N4) + lane;
    float4 a0 = make_float4(0.f, 0.f, 0.f, 0.f);
    float4 a1 = make_float4(0.f, 0.f, 0.f, 0.f);
#pragma unroll
    for (int i = 0; i + 2 <= LOADS; i += 2) {
      a0 = f4add(a0, p[(size_t)i * 64]);
      a1 = f4add(a1, p[(size_t)(i + 1) * 64]);
    }
    if (LOADS & 1) a0 = f4add(a0, p[(size_t)(LOADS - 1) * 64]);
    float4 r = f4add(a0, a1);
#pragma unroll
    for (int mask = N4; mask < 64; mask <<= 1) r = f4add(r, f4shfl_xor(r, mask));
    if (lane < N4)
      reinterpret_cast<float4*>(out)[out_base4 + b * N4 + col] = r;
  }
}

// Wave-level worklist (gw = global wave id), ~25-32KB contiguous per wave:
//   x0 [0,2048):    1 batch,  32 loads (M=128 N4=16)
//   x4 [2048,4096): 1 batch,  25 loads (M=200 N4=8)
//   x2 [4096,5120): 2 batches,16 loads each (M=64 N4=16)
//   x1 [5120,5376): 8 batches, 4 loads each (M=32 N4=8)
//   x3 [5376,5760): old column scheme, 16 loads (M=16 N4=12)
//   x5 [5760,5776): 128 batches, 32 loads (4 batches/load, M=8 N4=2)
__global__ __launch_bounds__(256) void ComboSumModule_25314537242674_kernel(
    const float* __restrict__ x0, const float* __restrict__ x1,
    const float* __restrict__ x2, const float* __restrict__ x3,
    const float* __restrict__ x4, const float* __restrict__ x5,
    float* __restrict__ out) {
  const int lane = threadIdx.x & 63;
  const int gw = blockIdx.x * 4 + (threadIdx.x >> 6);

  if (gw < 2048) {
    stream_sum<128, 16, 1>(x0, out, 0, gw, lane);
  } else if (gw < 4096) {
    stream_sum<200, 8, 1>(x4, out, 106496, gw - 2048, lane);
  } else if (gw < 5120) {
    stream_sum<64, 16, 2>(x2, out, 49152, (gw - 4096) * 2, lane);
  } else if (gw < 5376) {
    stream_sum<32, 8, 8>(x1, out, 32768, (gw - 5120) * 8, lane);
  } else if (gw < 5760) {
    // x3: M=16 N=48 (N4=12). Column scheme: u in [0,24576), full M per lane.
    const int u = (gw - 5376) * 64 + lane;
    const int b = u / 12;
    const int n4 = u - b * 12;
    const float4* __restrict__ p =
        reinterpret_cast<const float4*>(x3) + (size_t)b * 192 + n4;
    float4 a0 = make_float4(0.f, 0.f, 0.f, 0.f);
    float4 a1 = make_float4(0.f, 0.f, 0.f, 0.f);
#pragma unroll
    for (int i = 0; i < 16; i += 2) {
      a0 = f4add(a0, p[(size_t)i * 12]);
      a1 = f4add(a1, p[(size_t)(i + 1) * 12]);
    }
    reinterpret_cast<float4*>(out)[81920 + u] = f4add(a0, a1);
  } else {
    // x5: M=8 N=8 (N4=2). Each load covers 4 batches (16 f4 each).
    const int wi = gw - 5760;           // 0..15
    const int f = lane & 15;            // flat f4 idx within batch
    const int bs = lane >> 4;           // batch sub-index 0..3
    const float4* __restrict__ p =
        reinterpret_cast<const float4*>(x5) + (size_t)wi * 128 * 16 + lane;
#pragma unroll 4
    for (int j = 0; j < 32; ++j) {
      float4 r = p[(size_t)j * 64];
      r = f4add(r, f4shfl_xor(r, 2));
      r = f4add(r, f4shfl_xor(r, 4));
      r = f4add(r, f4shfl_xor(r, 8));
      if (f < 2) {
        const int b = wi * 128 + j * 4 + bs;
        reinterpret_cast<float4*>(out)[122880 + b * 2 + f] = r;
      }
    }
  }
}

extern "C" void kernel_launch(void* const* d_in, const int* in_sizes, int n_in,
                              void* d_out, int out_size, void* d_ws, size_t ws_size,
                              hipStream_t stream) {
  const float* x0 = (const float*)d_in[0];
  const float* x1 = (const float*)d_in[1];
  const float* x2 = (const float*)d_in[2];
  const float* x3 = (const float*)d_in[3];
  const float* x4 = (const float*)d_in[4];
  const float* x5 = (const float*)d_in[5];
  // d_in[6] is the python scalar dim=1; reduction axis baked in.
  float* out = (float*)d_out;

  // 5776 waves = 1444 blocks x 4 waves.
  ComboSumModule_25314537242674_kernel<<<1444, 256, 0, stream>>>(
      x0, x1, x2, x3, x4, x5, out);
}

// Round 7
// 177.735 us; speedup vs baseline: 1.0861x; 1.0861x over previous
//
#include <hip/hip_runtime.h>

// ComboSumModule: six independent sum-over-axis-1 reductions (f32).
// Shapes: (2048,128,64) (2048,32,32) (2048,64,64) (2048,16,48)
//         (2048,200,32) (2048,8,8). Outputs concatenated flat.
//
// R1-R6 post-mortem: all six kernels pinned at 58-76us / ~2.9 TB/s logical.
// Limiter = in-flight bytes/CU; compiler caps per-wave MLP at 2-3 loads no
// matter the source structure (VGPR 28..36 every round). R7: opaque inline
// asm -- one block of 8 global_load_dwordx4 + s_waitcnt vmcnt(0), so 8 KB
// per wave is GUARANTEED in flight. Worklist/LDS combine = R3 (best, 58us).

__device__ __forceinline__ float4 f4add(float4 a, float4 b) {
  return make_float4(a.x + b.x, a.y + b.y, a.z + b.z, a.w + b.w);
}

// 8 loads in flight, one drain. base: wave-uniform (SGPR pair); voff: per-lane
// byte offset; O1..O7: literal byte offsets (13-bit signed imm).
#define ASM_SUM8(r, base, voff, O1, O2, O3, O4, O5, O6, O7)                   \
  {                                                                           \
    float4 v0_, v1_, v2_, v3_, v4_, v5_, v6_, v7_;                            \
    asm volatile(                                                             \
        "global_load_dwordx4 %0, %8, %9\n\t"                                  \
        "global_load_dwordx4 %1, %8, %9 offset:" #O1 "\n\t"                   \
        "global_load_dwordx4 %2, %8, %9 offset:" #O2 "\n\t"                   \
        "global_load_dwordx4 %3, %8, %9 offset:" #O3 "\n\t"                   \
        "global_load_dwordx4 %4, %8, %9 offset:" #O4 "\n\t"                   \
        "global_load_dwordx4 %5, %8, %9 offset:" #O5 "\n\t"                   \
        "global_load_dwordx4 %6, %8, %9 offset:" #O6 "\n\t"                   \
        "global_load_dwordx4 %7, %8, %9 offset:" #O7 "\n\t"                   \
        "s_waitcnt vmcnt(0)"                                                  \
        : "=&v"(v0_), "=&v"(v1_), "=&v"(v2_), "=&v"(v3_), "=&v"(v4_),         \
          "=&v"(v5_), "=&v"(v6_), "=&v"(v7_)                                  \
        : "v"(voff), "s"(base)                                                \
        : "memory");                                                          \
    r = f4add(f4add(f4add(v0_, v1_), f4add(v2_, v3_)),                        \
              f4add(f4add(v4_, v5_), f4add(v6_, v7_)));                       \
  }

#define ASM_SUM5(r, base, voff, O1, O2, O3, O4)                               \
  {                                                                           \
    float4 v0_, v1_, v2_, v3_, v4_;                                           \
    asm volatile(                                                             \
        "global_load_dwordx4 %0, %5, %6\n\t"                                  \
        "global_load_dwordx4 %1, %5, %6 offset:" #O1 "\n\t"                   \
        "global_load_dwordx4 %2, %5, %6 offset:" #O2 "\n\t"                   \
        "global_load_dwordx4 %3, %5, %6 offset:" #O3 "\n\t"                   \
        "global_load_dwordx4 %4, %5, %6 offset:" #O4 "\n\t"                   \
        "s_waitcnt vmcnt(0)"                                                  \
        : "=&v"(v0_), "=&v"(v1_), "=&v"(v2_), "=&v"(v3_), "=&v"(v4_)          \
        : "v"(voff), "s"(base)                                                \
        : "memory");                                                          \
    r = f4add(f4add(f4add(v0_, v1_), f4add(v2_, v3_)), v4_);                  \
  }

#define ASM_SUM4(r, base, voff, O1, O2, O3)                                   \
  {                                                                           \
    float4 v0_, v1_, v2_, v3_;                                                \
    asm volatile(                                                             \
        "global_load_dwordx4 %0, %4, %5\n\t"                                  \
        "global_load_dwordx4 %1, %4, %5 offset:" #O1 "\n\t"                   \
        "global_load_dwordx4 %2, %4, %5 offset:" #O2 "\n\t"                   \
        "global_load_dwordx4 %3, %4, %5 offset:" #O3 "\n\t"                   \
        "s_waitcnt vmcnt(0)"                                                  \
        : "=&v"(v0_), "=&v"(v1_), "=&v"(v2_), "=&v"(v3_)                      \
        : "v"(voff), "s"(base)                                                \
        : "memory");                                                          \
    r = f4add(f4add(v0_, v1_), f4add(v2_, v3_));                              \
  }

// Combine WPG per-wave partials for a 64-unit group via LDS; lead wave
// stores. WPG==1 stores directly. Barrier reached by all 16 waves.
template <int WPG>
__device__ __forceinline__ void combine(float4 r, float* __restrict__ out,
                                        int out_base4, int group, int wave,
                                        int lane, float4* lds) {
  if (WPG == 1) {
    reinterpret_cast<float4*>(out)[out_base4 + group * 64 + lane] = r;
    return;
  }
  lds[wave * 64 + lane] = r;
  __syncthreads();
  if ((wave & (WPG - 1)) == 0) {
    float4 s = lds[wave * 64 + lane];
#pragma unroll
    for (int j = 1; j < WPG; ++j) s = f4add(s, lds[(wave + j) * 64 + lane]);
    reinterpret_cast<float4*>(out)[out_base4 + group * 64 + lane] = s;
  }
}

// Byte voffset for (group,lane) unit in a (2048, M, N4*4) tensor at row_start.
template <int M, int N4>
__device__ __forceinline__ int voffset(int group, int lane, int row_start) {
  const int u = group * 64 + lane;
  const int b = u / N4;  // const divisor -> magic-mul
  const int n4 = u - b * N4;
  return (b * (M * N4) + row_start * N4 + n4) * 16;
}

// Block order (heaviest first): x4 [0,256) x0 [256,768) x2 [768,1024)
// x1 [1024,1088) x3 [1088,1136) x5 [1136,1140). Region branch block-uniform.
__global__ __launch_bounds__(1024) void ComboSumModule_25314537242674_kernel(
    const float* __restrict__ x0, const float* __restrict__ x1,
    const float* __restrict__ x2, const float* __restrict__ x3,
    const float* __restrict__ x4, const float* __restrict__ x5,
    float* __restrict__ out) {
  __shared__ float4 lds[16 * 64];  // 16 KB
  const int lane = threadIdx.x & 63;
  const int wave = threadIdx.x >> 6;
  const int blk = blockIdx.x;

  if (blk < 256) {
    // x4: M=200 N4=8 (row stride 128B). Waves 0-7: 13 rows at 13w;
    // waves 8-15: 12 rows at 104+12(w-8). Split 8 + 5/4 loads.
    float4 r, r2;
    if (wave < 8) {
      const int vo = voffset<200, 8>(blk, lane, 13 * wave);
      ASM_SUM8(r, x4, vo, 128, 256, 384, 512, 640, 768, 896);
      ASM_SUM5(r2, x4, vo + 1024, 128, 256, 384, 512);
    } else {
      const int vo = voffset<200, 8>(blk, lane, 104 + 12 * (wave - 8));
      ASM_SUM8(r, x4, vo, 128, 256, 384, 512, 640, 768, 896);
      ASM_SUM4(r2, x4, vo + 1024, 128, 256, 384);
    }
    combine<16>(f4add(r, r2), out, 106496, blk, wave, lane, lds);
  } else if (blk < 768) {
    // x0: M=128 N4=16 (row stride 256B), wave w rows [8w, 8w+8).
    const int g = blk - 256;
    float4 r;
    const int vo = voffset<128, 16>(g, lane, 8 * wave);
    ASM_SUM8(r, x0, vo, 256, 512, 768, 1024, 1280, 1536, 1792);
    combine<16>(r, out, 0, g, wave, lane, lds);
  } else if (blk < 1024) {
    // x2: M=64 N4=16 (row stride 256B), 2 groups/block, 8 waves each.
    const int g = (blk - 768) * 2 + (wave >> 3);
    float4 r;
    const int vo = voffset<64, 16>(g, lane, 8 * (wave & 7));
    ASM_SUM8(r, x2, vo, 256, 512, 768, 1024, 1280, 1536, 1792);
    combine<8>(r, out, 49152, g, wave, lane, lds);
  } else if (blk < 1088) {
    // x1: M=32 N4=8 (row stride 128B), 4 groups/block, 4 waves each.
    const int g = (blk - 1024) * 4 + (wave >> 2);
    float4 r;
    const int vo = voffset<32, 8>(g, lane, 8 * (wave & 3));
    ASM_SUM8(r, x1, vo, 128, 256, 384, 512, 640, 768, 896);
    combine<4>(r, out, 32768, g, wave, lane, lds);
  } else if (blk < 1136) {
    // x3: M=16 N4=12 (row stride 192B), 8 groups/block, 2 waves each.
    const int g = (blk - 1088) * 8 + (wave >> 1);
    float4 r;
    const int vo = voffset<16, 12>(g, lane, 8 * (wave & 1));
    ASM_SUM8(r, x3, vo, 192, 384, 576, 768, 960, 1152, 1344);
    combine<2>(r, out, 81920, g, wave, lane, lds);
  } else {
    // x5: M=8 N4=2 (row stride 32B), 16 groups/block, 1 wave, full M.
    const int g = (blk - 1136) * 16 + wave;
    float4 r;
    const int vo = voffset<8, 2>(g, lane, 0);
    ASM_SUM8(r, x5, vo, 32, 64, 96, 128, 160, 192, 224);
    combine<1>(r, out, 122880, g, wave, lane, lds);
  }
}

extern "C" void kernel_launch(void* const* d_in, const int* in_sizes, int n_in,
                              void* d_out, int out_size, void* d_ws, size_t ws_size,
                              hipStream_t stream) {
  const float* x0 = (const float*)d_in[0];
  const float* x1 = (const float*)d_in[1];
  const float* x2 = (const float*)d_in[2];
  const float* x3 = (const float*)d_in[3];
  const float* x4 = (const float*)d_in[4];
  const float* x5 = (const float*)d_in[5];
  // d_in[6] is the python scalar dim=1; reduction axis baked in.
  float* out = (float*)d_out;

  ComboSumModule_25314537242674_kernel<<<1140, 1024, 0, stream>>>(
      x0, x1, x2, x3, x4, x5, out);
}